// Round 1
// 675.783 us; speedup vs baseline: 1.0685x; 1.0685x over previous
//
#include <hip/hip_runtime.h>
#include <math.h>

typedef __attribute__((ext_vector_type(8))) short s16x8;   // 8 bf16 (4 VGPRs)
typedef __attribute__((ext_vector_type(4))) float f32x4;

__device__ inline ushort f2bf(float f) {
    union { float f; unsigned u; } v; v.f = f;
    unsigned r = v.u + 0x7FFF + ((v.u >> 16) & 1);   // RTN-even
    return (ushort)(r >> 16);
}
__device__ inline float bf2f(ushort h) {
    union { unsigned u; float f; } v; v.u = ((unsigned)h) << 16;
    return v.f;
}
__device__ inline float bfLo(unsigned u) {   // element at even index (low half)
    union { unsigned x; float f; } v; v.x = u << 16; return v.f;
}
__device__ inline float bfHi(unsigned u) {   // element at odd index (high half)
    union { unsigned x; float f; } v; v.x = u & 0xFFFF0000u; return v.f;
}

// ---------------- CSR build ----------------

__global__ void hist_kernel(const int* __restrict__ dst, int E, int* __restrict__ cnt) {
    int e = blockIdx.x * blockDim.x + threadIdx.x;
    if (e < E) atomicAdd(&cnt[dst[e]], 1);
}

__global__ void alloc_kernel(const int* __restrict__ cnt, int* __restrict__ row_start,
                             float* __restrict__ dinv, int* __restrict__ total, int N) {
    int i = blockIdx.x * blockDim.x + threadIdx.x;
    int lane = threadIdx.x & 63;
    int c = (i < N) ? cnt[i] : 0;
    int inc = c;
#pragma unroll
    for (int o = 1; o < 64; o <<= 1) {
        int v = __shfl_up(inc, o, 64);
        if (lane >= o) inc += v;
    }
    int wsum = __shfl(inc, 63, 64);
    int base = 0;
    if (lane == 0) base = atomicAdd(total, wsum);
    base = __shfl(base, 0, 64);
    if (i < N) {
        row_start[i] = base + inc - c;
        dinv[i] = rsqrtf((float)(c + 1));
    }
}

__global__ void scatter_kernel(const int* __restrict__ src, const int* __restrict__ dst, int E,
                               const int* __restrict__ row_start, int* __restrict__ cursor,
                               int* __restrict__ csr) {
    int e = blockIdx.x * blockDim.x + threadIdx.x;
    if (e < E) {
        int d = dst[e];
        int p = row_start[d] + atomicAdd(&cursor[d], 1);
        csr[p] = src[e];
    }
}

// ---------------- W1^T hi/lo split precompute: wt[n][k] bf16 ----------------
__global__ void wsplit_kernel(const float* __restrict__ W, ushort* __restrict__ wt_hi,
                              ushort* __restrict__ wt_lo) {
    int idx = blockIdx.x * blockDim.x + threadIdx.x;
    if (idx < 64 * 512) {
        int n = idx & 63, k = idx >> 6;           // read coalesced over n
        float f = W[k * 64 + n];
        ushort h = f2bf(f);
        wt_hi[n * 512 + k] = h;
        wt_lo[n * 512 + k] = f2bf(f - bf2f(h));
    }
}

// ---------------- W2^T hi/lo split precompute: wt2[n][k] bf16, n=0..255 k=0..63 --------
__global__ void w2split_kernel(const float* __restrict__ W, ushort* __restrict__ wt_hi,
                               ushort* __restrict__ wt_lo) {
    int idx = blockIdx.x * blockDim.x + threadIdx.x;
    if (idx < 64 * 256) {
        int n = idx & 255, k = idx >> 8;          // read coalesced over n
        float f = W[k * 256 + n];
        ushort h = f2bf(f);
        wt_hi[n * 64 + k] = h;
        wt_lo[n * 64 + k] = f2bf(f - bf2f(h));
    }
}

// ---------------- GEMM1 (MFMA): p = dinv * (x @ W1) as bf16, hi/lo 3-term split ----------
__global__ __launch_bounds__(256, 3) void gemm1_kernel(const float* __restrict__ x,
                                                       const ushort* __restrict__ wt_hi,
                                                       const ushort* __restrict__ wt_lo,
                                                       const float* __restrict__ dinv,
                                                       ushort* __restrict__ out, int N) {
    __shared__ __align__(16) short xs_hi[128 * 64];   // 16 KB  [node][g'*8+j]
    __shared__ __align__(16) short xs_lo[128 * 64];   // 16 KB
    __shared__ __align__(16) short ws_hi[64 * 64];    //  8 KB  [n][g'*8+j]
    __shared__ __align__(16) short ws_lo[64 * 64];    //  8 KB

    const int tid = threadIdx.x;
    const int nodeBase = blockIdx.x * 128;
    const int wave = tid >> 6, lane = tid & 63;
    const int m16 = lane & 15, quad = lane >> 4;

    f32x4 acc[2][4];
#pragma unroll
    for (int mt = 0; mt < 2; mt++)
#pragma unroll
        for (int nt = 0; nt < 4; nt++) acc[mt][nt] = (f32x4){0.f, 0.f, 0.f, 0.f};

    for (int kc = 0; kc < 512; kc += 64) {
        __syncthreads();
#pragma unroll
        for (int i = 0; i < 4; i++) {
            int f = tid + i * 256;            // 0..1023
            int node = f >> 3, g = f & 7;
            int gn = nodeBase + node;
            if (gn >= N) gn = N - 1;
            const float4 a = *(const float4*)(x + (size_t)gn * 512 + kc + g * 8);
            const float4 b = *(const float4*)(x + (size_t)gn * 512 + kc + g * 8 + 4);
            float ff[8] = {a.x, a.y, a.z, a.w, b.x, b.y, b.z, b.w};
            union { ushort u[8]; uint4 v; } H, L;
#pragma unroll
            for (int j = 0; j < 8; j++) {
                ushort h = f2bf(ff[j]);
                H.u[j] = h;
                L.u[j] = f2bf(ff[j] - bf2f(h));
            }
            int gp = (g + node) & 7;
            *(uint4*)&xs_hi[node * 64 + gp * 8] = H.v;
            *(uint4*)&xs_lo[node * 64 + gp * 8] = L.v;
        }
#pragma unroll
        for (int i = 0; i < 2; i++) {
            int f = tid + i * 256;            // 0..511
            int n = f >> 3, g = f & 7;
            int gp = (g + n) & 7;
            *(uint4*)&ws_hi[n * 64 + gp * 8] =
                *(const uint4*)(wt_hi + (size_t)n * 512 + kc + g * 8);
            *(uint4*)&ws_lo[n * 64 + gp * 8] =
                *(const uint4*)(wt_lo + (size_t)n * 512 + kc + g * 8);
        }
        __syncthreads();
#pragma unroll
        for (int ck = 0; ck < 2; ck++) {
            s16x8 Ah[2], Al[2];
#pragma unroll
            for (int mt = 0; mt < 2; mt++) {
                int row = (wave * 2 + mt) * 16 + m16;     // local 0..127
                int gp = (ck * 4 + quad + row) & 7;
                Ah[mt] = *(s16x8*)&xs_hi[row * 64 + gp * 8];
                Al[mt] = *(s16x8*)&xs_lo[row * 64 + gp * 8];
            }
#pragma unroll
            for (int nt = 0; nt < 4; nt++) {
                int n = nt * 16 + m16;                    // local 0..63
                int gp = (ck * 4 + quad + n) & 7;
                s16x8 Bh = *(s16x8*)&ws_hi[n * 64 + gp * 8];
                s16x8 Bl = *(s16x8*)&ws_lo[n * 64 + gp * 8];
#pragma unroll
                for (int mt = 0; mt < 2; mt++) {
                    acc[mt][nt] = __builtin_amdgcn_mfma_f32_16x16x32_bf16(Ah[mt], Bh, acc[mt][nt], 0, 0, 0);
                    acc[mt][nt] = __builtin_amdgcn_mfma_f32_16x16x32_bf16(Ah[mt], Bl, acc[mt][nt], 0, 0, 0);
                    acc[mt][nt] = __builtin_amdgcn_mfma_f32_16x16x32_bf16(Al[mt], Bh, acc[mt][nt], 0, 0, 0);
                }
            }
        }
    }
    // C/D layout: col = lane&15, row = quad*4 + reg. Write p = dinv*acc as bf16.
#pragma unroll
    for (int mt = 0; mt < 2; mt++) {
#pragma unroll
        for (int r = 0; r < 4; r++) {
            int gn = nodeBase + (wave * 2 + mt) * 16 + quad * 4 + r;
            if (gn < N) {
                float di = dinv[gn];
#pragma unroll
                for (int nt = 0; nt < 4; nt++)
                    out[(size_t)gn * 64 + nt * 16 + m16] = f2bf(di * acc[mt][nt][r]);
            }
        }
    }
}

// ---------------- 64-dim CSR aggregation over premultiplied bf16 table ----------------
// out[i] = post( dinv[i] * (in[i] + sum_j in[j]) ), one wave per node, lane = feature.
template <int RELU, int BIAS, int PREMUL>
__global__ void agg64bf_kernel(const ushort* __restrict__ in, ushort* __restrict__ out,
                               const int* __restrict__ row_start, const int* __restrict__ cnt,
                               const int* __restrict__ csr, const float* __restrict__ dinv,
                               const float* __restrict__ bias, int N) {
    int gw = (int)((blockIdx.x * (size_t)blockDim.x + threadIdx.x) >> 6);
    int lane = threadIdx.x & 63;
    if (gw >= N) return;
    float acc = bf2f(in[(size_t)gw * 64 + lane]);   // self loop (already premultiplied)
    int s = row_start[gw];
    int c = cnt[gw];
    int e = 0;
    for (; e + 8 <= c; e += 8) {   // 8 gathers in flight
        int j0 = csr[s + e + 0], j1 = csr[s + e + 1], j2 = csr[s + e + 2], j3 = csr[s + e + 3];
        int j4 = csr[s + e + 4], j5 = csr[s + e + 5], j6 = csr[s + e + 6], j7 = csr[s + e + 7];
        float v0 = bf2f(in[(size_t)j0 * 64 + lane]);
        float v1 = bf2f(in[(size_t)j1 * 64 + lane]);
        float v2 = bf2f(in[(size_t)j2 * 64 + lane]);
        float v3 = bf2f(in[(size_t)j3 * 64 + lane]);
        float v4 = bf2f(in[(size_t)j4 * 64 + lane]);
        float v5 = bf2f(in[(size_t)j5 * 64 + lane]);
        float v6 = bf2f(in[(size_t)j6 * 64 + lane]);
        float v7 = bf2f(in[(size_t)j7 * 64 + lane]);
        acc += ((v0 + v1) + (v2 + v3)) + ((v4 + v5) + (v6 + v7));
    }
    for (; e < c; e++) {
        int j = csr[s + e];
        acc += bf2f(in[(size_t)j * 64 + lane]);
    }
    float di = dinv[gw];
    float v = di * acc;
    if (BIAS) v += bias[lane];
    if (RELU) v = fmaxf(v, 0.f);
    if (PREMUL) v *= di;
    out[(size_t)gw * 64 + lane] = f2bf(v);
}

// ---------------- fused GEMM2 (+bias,relu) + GEMM3, MFMA version ----------------
// r[i] = dinv[i] * (relu(a2[i] @ W2 + b2) @ W3)
// a2 is ALREADY bf16 (exact A operand). W2 split into bf16 hi/lo (2-term).
// Fragments loaded directly from global (rows of 64 bf16 = 128 B match the MFMA
// fragment stride); no LDS, no barriers. W2^T hi/lo (128 KB) stays L2-resident.
__global__ __launch_bounds__(256, 2) void gemm23_kernel(const ushort* __restrict__ a2,
                                                        const ushort* __restrict__ wt2_hi,
                                                        const ushort* __restrict__ wt2_lo,
                                                        const float* __restrict__ b2,
                                                        const float* __restrict__ W3,
                                                        const float* __restrict__ dinv,
                                                        float* __restrict__ r, int N) {
    const int tid = threadIdx.x;
    const int wave = tid >> 6, lane = tid & 63;
    const int m16 = lane & 15, quad = lane >> 4;
    const int rowBase = blockIdx.x * 128 + wave * 32;   // wave covers 32 nodes

    // A fragments: row = rowBase + mt*16 + m16, k = ck*32 + quad*8 .. +8
    s16x8 A[2][2];
#pragma unroll
    for (int mt = 0; mt < 2; mt++) {
        int gn = rowBase + mt * 16 + m16;
        if (gn >= N) gn = N - 1;
        const ushort* ap = a2 + (size_t)gn * 64 + quad * 8;
#pragma unroll
        for (int ck = 0; ck < 2; ck++)
            A[mt][ck] = *(const s16x8*)(ap + ck * 32);
    }

    f32x4 acc[2][16];
#pragma unroll
    for (int mt = 0; mt < 2; mt++)
#pragma unroll
        for (int nt = 0; nt < 16; nt++) acc[mt][nt] = (f32x4){0.f, 0.f, 0.f, 0.f};

#pragma unroll
    for (int nt = 0; nt < 16; nt++) {
        int n = nt * 16 + m16;                           // output col 0..255
        const ushort* bh = wt2_hi + (size_t)n * 64 + quad * 8;
        const ushort* bl = wt2_lo + (size_t)n * 64 + quad * 8;
        s16x8 Bh0 = *(const s16x8*)(bh);
        s16x8 Bh1 = *(const s16x8*)(bh + 32);
        s16x8 Bl0 = *(const s16x8*)(bl);
        s16x8 Bl1 = *(const s16x8*)(bl + 32);
        acc[0][nt] = __builtin_amdgcn_mfma_f32_16x16x32_bf16(A[0][0], Bh0, acc[0][nt], 0, 0, 0);
        acc[1][nt] = __builtin_amdgcn_mfma_f32_16x16x32_bf16(A[1][0], Bh0, acc[1][nt], 0, 0, 0);
        acc[0][nt] = __builtin_amdgcn_mfma_f32_16x16x32_bf16(A[0][1], Bh1, acc[0][nt], 0, 0, 0);
        acc[1][nt] = __builtin_amdgcn_mfma_f32_16x16x32_bf16(A[1][1], Bh1, acc[1][nt], 0, 0, 0);
        acc[0][nt] = __builtin_amdgcn_mfma_f32_16x16x32_bf16(A[0][0], Bl0, acc[0][nt], 0, 0, 0);
        acc[1][nt] = __builtin_amdgcn_mfma_f32_16x16x32_bf16(A[1][0], Bl0, acc[1][nt], 0, 0, 0);
        acc[0][nt] = __builtin_amdgcn_mfma_f32_16x16x32_bf16(A[0][1], Bl1, acc[0][nt], 0, 0, 0);
        acc[1][nt] = __builtin_amdgcn_mfma_f32_16x16x32_bf16(A[1][1], Bl1, acc[1][nt], 0, 0, 0);
    }

    // epilogue: per lane holds cols {nt*16+m16} of rows {mt*16+quad*4+rr}
    float bv[16], wv[16];
#pragma unroll
    for (int nt = 0; nt < 16; nt++) {
        bv[nt] = b2[nt * 16 + m16];
        wv[nt] = W3[nt * 16 + m16];
    }
#pragma unroll
    for (int mt = 0; mt < 2; mt++) {
#pragma unroll
        for (int rr = 0; rr < 4; rr++) {
            float p = 0.f;
#pragma unroll
            for (int nt = 0; nt < 16; nt++) {
                float v = fmaxf(acc[mt][nt][rr] + bv[nt], 0.f);
                p = fmaf(v, wv[nt], p);
            }
            // reduce the 16-lane m16 group (same quad = same row)
#pragma unroll
            for (int off = 1; off < 16; off <<= 1) p += __shfl_xor(p, off, 64);
            int gn = rowBase + mt * 16 + quad * 4 + rr;
            if (m16 == 0 && gn < N) r[gn] = dinv[gn] * p;
        }
    }
}

// ---------------- scalar aggregation of premultiplied r + BCE loss + mean reduce --------
__global__ void loss_kernel(const float* __restrict__ r, const float* __restrict__ dinv,
                            const int* __restrict__ row_start, const int* __restrict__ cnt,
                            const int* __restrict__ csr, const float* __restrict__ y,
                            const float* __restrict__ b3, float* __restrict__ out,
                            int N, float invN) {
    int i = blockIdx.x * blockDim.x + threadIdx.x;
    float loss = 0.f;
    if (i < N) {
        float aedge = r[i];
        int s = row_start[i], c = cnt[i];
        int e = 0;
        for (; e + 4 <= c; e += 4) {
            int j0 = csr[s + e + 0], j1 = csr[s + e + 1];
            int j2 = csr[s + e + 2], j3 = csr[s + e + 3];
            aedge += (r[j0] + r[j1]) + (r[j2] + r[j3]);
        }
        for (; e < c; e++) aedge += r[csr[s + e]];
        float z = dinv[i] * aedge + b3[0];
        float yv = y[i];
        float L = log1pf(expf(-fabsf(z)));
        float spz  = fmaxf(z, 0.f) + L;    // softplus(z)
        float spnz = fmaxf(-z, 0.f) + L;   // softplus(-z)
        loss = yv * spnz + (1.f - yv) * spz;
    }
#pragma unroll
    for (int off = 32; off > 0; off >>= 1) loss += __shfl_down(loss, off, 64);
    __shared__ float red[4];
    int lane = threadIdx.x & 63, wave = threadIdx.x >> 6;
    if (lane == 0) red[wave] = loss;
    __syncthreads();
    if (threadIdx.x == 0)
        atomicAdd(out, (red[0] + red[1] + red[2] + red[3]) * invN);
}

// ---------------- launch ----------------
extern "C" void kernel_launch(void* const* d_in, const int* in_sizes, int n_in,
                              void* d_out, int out_size, void* d_ws, size_t ws_size,
                              hipStream_t stream) {
    const float* x  = (const float*)d_in[0];
    const int*   ei = (const int*)d_in[1];
    const float* y  = (const float*)d_in[2];
    const float* W1 = (const float*)d_in[3];
    const float* b1 = (const float*)d_in[4];
    const float* W2 = (const float*)d_in[5];
    const float* b2 = (const float*)d_in[6];
    const float* W3 = (const float*)d_in[7];
    const float* b3 = (const float*)d_in[8];

    const int N = in_sizes[2];        // y has N elements
    const int E = in_sizes[1] / 2;
    const int* src  = ei;
    const int* dstp = ei + E;

    char* w = (char*)d_ws;
    int*    cnt       = (int*)w;    w += (size_t)N * 4;
    int*    cursor    = (int*)w;    w += (size_t)N * 4;
    int*    total     = (int*)w;    w += 16;
    int*    row_start = (int*)w;    w += (size_t)N * 4;
    float*  dinv      = (float*)w;  w += (size_t)N * 4;
    int*    csr       = (int*)w;    w += (size_t)E * 4;
    ushort* wt_hi     = (ushort*)w; w += (size_t)64 * 512 * 2;
    ushort* wt_lo     = (ushort*)w; w += (size_t)64 * 512 * 2;
    ushort* wt2_hi    = (ushort*)w; w += (size_t)256 * 64 * 2;
    ushort* wt2_lo    = (ushort*)w; w += (size_t)256 * 64 * 2;
    ushort* pbuf      = (ushort*)w; w += (size_t)N * 64 * 2;   // p, later a2
    ushort* qbuf      = (ushort*)w; w += (size_t)N * 64 * 2;   // q
    float*  rbuf      = (float*)w;  w += (size_t)N * 4;        // r = dinv*t

    hipMemsetAsync(cnt, 0, (size_t)N * 8 + 16, stream);
    hipMemsetAsync(d_out, 0, sizeof(float), stream);

    const int tb = 256;
    wsplit_kernel<<<(64 * 512 + tb - 1) / tb, tb, 0, stream>>>(W1, wt_hi, wt_lo);
    w2split_kernel<<<(64 * 256 + tb - 1) / tb, tb, 0, stream>>>(W2, wt2_hi, wt2_lo);
    hist_kernel<<<(E + tb - 1) / tb, tb, 0, stream>>>(dstp, E, cnt);
    alloc_kernel<<<(N + tb - 1) / tb, tb, 0, stream>>>(cnt, row_start, dinv, total, N);
    scatter_kernel<<<(E + tb - 1) / tb, tb, 0, stream>>>(src, dstp, E, row_start, cursor, csr);

    // layer 1: p = dinv * (x @ W1) as bf16
    gemm1_kernel<<<(N + 127) / 128, 256, 0, stream>>>(x, wt_hi, wt_lo, dinv, pbuf, N);
    // q = dinv * relu(dinv * (p_self + sum p_nbr) + b1)
    agg64bf_kernel<1, 1, 1><<<(N + 3) / 4, 256, 0, stream>>>(pbuf, qbuf, row_start, cnt, csr, dinv, b1, N);
    // a2 = dinv * (q_self + sum q_nbr)   (reuses pbuf)
    agg64bf_kernel<0, 0, 0><<<(N + 3) / 4, 256, 0, stream>>>(qbuf, pbuf, row_start, cnt, csr, dinv, nullptr, N);

    // layers 2+3 fused via MFMA: r = dinv * (relu(a2 @ W2 + b2) @ W3)
    gemm23_kernel<<<(N + 127) / 128, 256, 0, stream>>>(pbuf, wt2_hi, wt2_lo, b2, W3, dinv, rbuf, N);

    // layer 3 aggregation (scalar, premultiplied) + BCE + mean
    loss_kernel<<<(N + tb - 1) / tb, tb, 0, stream>>>(rbuf, dinv, row_start, cnt, csr, y, b3,
                                                      (float*)d_out, N, 1.0f / N);
}